// Round 4
// baseline (154.012 us; speedup 1.0000x reference)
//
#include <hip/hip_runtime.h>
#include <hip/hip_bf16.h>

// out[b,s,h] = word_emb[input_ids[b,s]][h] + type_emb[token_type_ids[b,s]][h] + pos_emb[s][h]
// H = 768 floats = 192 float4 per row. One wave (64 lanes) per token; each
// lane handles 3 float4 (48 B) -> fully coalesced 3072 B row read/write.
// All 9 loads issued before compute (MLP); out written with nontemporal
// stores so the streamed output doesn't evict the L3-resident word table.
// Native clang vector type (ext_vector_type) because __builtin_nontemporal_store
// rejects HIP_vector_type<float,4>.

typedef float f32x4 __attribute__((ext_vector_type(4)));

#define HIDDEN4 192   // 768 / 4
#define SEQ     512

__global__ __launch_bounds__(256) void BertEmbedding_77670188581156_kernel(
    const int* __restrict__ input_ids,
    const int* __restrict__ token_type_ids,
    const f32x4* __restrict__ word_emb,
    const f32x4* __restrict__ pos_emb,
    const f32x4* __restrict__ type_emb,
    f32x4* __restrict__ out,
    int n_tokens) {
    const int wave  = (blockIdx.x * blockDim.x + threadIdx.x) >> 6;  // token index
    const int lane  = threadIdx.x & 63;
    if (wave >= n_tokens) return;

    const int token = wave;
    const int id  = input_ids[token];       // wave-uniform broadcast load
    const int tt  = token_type_ids[token];
    const int s   = token & (SEQ - 1);      // position within sequence

    const f32x4* __restrict__ wrow = word_emb + (size_t)id * HIDDEN4 + lane;
    const f32x4* __restrict__ prow = pos_emb  + (size_t)s  * HIDDEN4 + lane;
    const f32x4* __restrict__ trow = type_emb + (size_t)tt * HIDDEN4 + lane;
    f32x4* __restrict__ orow       = out      + (size_t)token * HIDDEN4 + lane;

    // Issue all 9 vector loads before any dependent compute.
    const f32x4 w0 = wrow[0],   w1 = wrow[64],  w2 = wrow[128];
    const f32x4 p0 = prow[0],   p1 = prow[64],  p2 = prow[128];
    const f32x4 t0 = trow[0],   t1 = trow[64],  t2 = trow[128];

    const f32x4 r0 = w0 + p0 + t0;
    const f32x4 r1 = w1 + p1 + t1;
    const f32x4 r2 = w2 + p2 + t2;

    __builtin_nontemporal_store(r0, &orow[0]);
    __builtin_nontemporal_store(r1, &orow[64]);
    __builtin_nontemporal_store(r2, &orow[128]);
}

extern "C" void kernel_launch(void* const* d_in, const int* in_sizes, int n_in,
                              void* d_out, int out_size, void* d_ws, size_t ws_size,
                              hipStream_t stream) {
    const int*   input_ids      = (const int*)d_in[0];
    const int*   token_type_ids = (const int*)d_in[1];
    const f32x4* word_emb       = (const f32x4*)d_in[2];
    const f32x4* pos_emb        = (const f32x4*)d_in[3];
    const f32x4* type_emb       = (const f32x4*)d_in[4];
    f32x4*       out            = (f32x4*)d_out;

    const int n_tokens = in_sizes[0];            // 32 * 512 = 16384
    const int waves_per_block = 256 / 64;        // 4 tokens per block
    const int grid = (n_tokens + waves_per_block - 1) / waves_per_block;

    BertEmbedding_77670188581156_kernel<<<grid, 256, 0, stream>>>(
        input_ids, token_type_ids, word_emb, pos_emb, type_emb, out, n_tokens);
}